// Round 8
// baseline (354.613 us; speedup 1.0000x reference)
//
#include <hip/hip_runtime.h>
#include <math.h>

// Problem constants
#define NB   64
#define TT   2048
// Tail-window truncation (validated R6/R7): output = x[:,2047]; only temporal
// coupling is the LIF membrane (decay 0.5/step + hard reset). v(T0)=0 with
// TW=64 perturbs output decisions by ~0.5^63 — absmax matched full scan.
#define TW   64
#define T0   (TT - TW)

// The whole post-projector pipeline factorizes over batch b (fc/LN per row,
// LIF per (b,chan) chain, residual per row, out per b). One workgroup per
// batch runs all stages with __syncthreads only -> single kernel launch.
//
// Memory discipline inside the fused kernel:
//  - W tiles: LDS (staged 64KB halves) -> per-lane ds_read      (R3 lesson)
//  - x rows: wave-uniform VECTOR loads via asm-opaque pointer. NOT s_load:
//    the scalar K$ is not coherent with this kernel's own vector writes
//    (stale across layers). NOT LDS: broadcast ds_reads choke the LDS pipe
//    (R2 lesson). Same-address lane loads are HW-broadcast, 1 issue on vmem.

__device__ __forceinline__ float gelu_exact(float x) {
    return 0.5f * x * (1.0f + erff(x * 0.7071067811865476f));
}

// Route a pointer through a VGPR so the compiler cannot prove uniformity ->
// forces global_load (vector path, L2-coherent with our own prior stores).
__device__ __forceinline__ const float* vptr(const float* p) {
    asm volatile("" : "+v"(p));
    return p;
}

__global__ __launch_bounds__(1024, 4) void mega_kernel(
        const float* __restrict__ hist,
        const float* __restrict__ pw1, const float* __restrict__ pb1,
        const float* __restrict__ pw2, const float* __restrict__ pb2,
        const float* __restrict__ fc1w, const float* __restrict__ fc1b,
        const float* __restrict__ n1g, const float* __restrict__ n1b,
        const float* __restrict__ fc2w, const float* __restrict__ fc2b,
        const float* __restrict__ n2g, const float* __restrict__ n2b,
        float* X, float* H, float* Y, float* G, float* out)
{
    __shared__ float Wc[64*256];                 // 64 KB weight staging
    const int t    = threadIdx.x;                // 1024 threads = 16 waves
    const int b    = blockIdx.x;                 // one workgroup per batch
    const int wv   = t >> 6, lane = t & 63;
    const int r0   = wv * 4;                     // each wave owns 4 rows (t-idx)

    float* Gb = G + (size_t)b * TW * 64;
    float* Xb = X + (size_t)b * TW * 128;
    float* Hb = H + (size_t)b * TW * 256;
    float* Yb = Y + (size_t)b * TW * 128;

    // ---------------- P1: G = gelu(hist @ pw1 + pb1)  [TW,64] ---------------
    {
        const float* hb = hist + ((size_t)b * TT + T0) * 4;   // read-only input
        #pragma unroll
        for (int rr = 0; rr < 4; ++rr) {
            int r = r0 + rr;
            float h0 = hb[r*4+0], h1 = hb[r*4+1], h2 = hb[r*4+2], h3 = hb[r*4+3];
            float a = pb1[lane] + h0*pw1[lane] + h1*pw1[64+lane]
                                + h2*pw1[128+lane] + h3*pw1[192+lane];
            Gb[r*64 + lane] = gelu_exact(a);
        }
    }
    // ---------------- P2: X = G @ pw2 + pb2  [TW,128] -----------------------
    __syncthreads();
    for (int i = t; i < 64*128/4; i += 1024)
        ((float4*)Wc)[i] = ((const float4*)pw2)[i];
    __syncthreads();
    {
        const float* Gv = vptr(Gb);
        float2 bv = ((const float2*)pb2)[lane];
        float2 acc[4];
        #pragma unroll
        for (int rr = 0; rr < 4; ++rr) acc[rr] = make_float2(0.f, 0.f);
        #pragma unroll 2
        for (int k4 = 0; k4 < 16; ++k4) {
            float4 xr[4];
            #pragma unroll
            for (int rr = 0; rr < 4; ++rr)
                xr[rr] = *(const float4*)(Gv + (r0+rr)*64 + k4*4);  // broadcast
            #pragma unroll
            for (int kk = 0; kk < 4; ++kk) {
                float2 w = ((const float2*)(Wc + (k4*4 + kk)*128))[lane];
                #pragma unroll
                for (int rr = 0; rr < 4; ++rr) {
                    float xv = ((const float*)&xr[rr])[kk];
                    acc[rr].x += xv * w.x;
                    acc[rr].y += xv * w.y;
                }
            }
        }
        #pragma unroll
        for (int rr = 0; rr < 4; ++rr) {
            float2 o; o.x = acc[rr].x + bv.x; o.y = acc[rr].y + bv.y;
            ((float2*)(Xb + (size_t)(r0+rr)*128))[lane] = o;
        }
    }

    // ---------------- 4 residual blocks -------------------------------------
    for (int l = 0; l < 4; ++l) {
        // ---- fc1: H = LN(X @ W1 + b1)  [TW,256] ----
        float4 facc[4];
        #pragma unroll
        for (int rr = 0; rr < 4; ++rr) facc[rr] = make_float4(0.f,0.f,0.f,0.f);
        {
            const float* Xv = vptr(Xb);
            for (int h = 0; h < 2; ++h) {
                __syncthreads();                 // Wc free (prev readers done)
                const float4* Wh = (const float4*)(fc1w + (size_t)l*32768 + h*16384);
                for (int i = t; i < 4096; i += 1024) ((float4*)Wc)[i] = Wh[i];
                __syncthreads();
                #pragma unroll 2
                for (int k4 = 0; k4 < 16; ++k4) {
                    float4 xr[4];
                    #pragma unroll
                    for (int rr = 0; rr < 4; ++rr)
                        xr[rr] = *(const float4*)(Xv + (r0+rr)*128 + h*64 + k4*4);
                    #pragma unroll
                    for (int kk = 0; kk < 4; ++kk) {
                        float4 w = ((const float4*)(Wc + (k4*4 + kk)*256))[lane];
                        #pragma unroll
                        for (int rr = 0; rr < 4; ++rr) {
                            float xv = ((const float*)&xr[rr])[kk];
                            facc[rr].x += xv * w.x; facc[rr].y += xv * w.y;
                            facc[rr].z += xv * w.z; facc[rr].w += xv * w.w;
                        }
                    }
                }
            }
        }
        {
            float4 bv  = ((const float4*)(fc1b + l*256))[lane];
            float4 gv  = ((const float4*)(n1g  + l*256))[lane];
            float4 btv = ((const float4*)(n1b  + l*256))[lane];
            #pragma unroll
            for (int rr = 0; rr < 4; ++rr) {
                float4 a = facc[rr];
                a.x += bv.x; a.y += bv.y; a.z += bv.z; a.w += bv.w;
                float s = a.x + a.y + a.z + a.w;
                #pragma unroll
                for (int m = 1; m < 64; m <<= 1) s += __shfl_xor(s, m, 64);
                float mean = s * (1.0f/256.0f);
                float dx = a.x-mean, dy = a.y-mean, dz = a.z-mean, dw = a.w-mean;
                float q = dx*dx + dy*dy + dz*dz + dw*dw;
                #pragma unroll
                for (int m = 1; m < 64; m <<= 1) q += __shfl_xor(q, m, 64);
                float inv = 1.0f / sqrtf(q * (1.0f/256.0f) + 1e-5f);
                float4 o;
                o.x = dx*inv*gv.x + btv.x; o.y = dy*inv*gv.y + btv.y;
                o.z = dz*inv*gv.z + btv.z; o.w = dw*inv*gv.w + btv.w;
                ((float4*)(Hb + (size_t)(r0+rr)*256))[lane] = o;
            }
        }
        __syncthreads();
        // ---- lif1: H -> spike floats in place (256 chains, t-serial) ----
        if (t < 256) {
            float* p = Hb + t;                   // per-lane addresses -> vector
            float v = 0.f;
            #pragma unroll 8
            for (int i = 0; i < TW; ++i) {
                float x = p[i*256];
                v += (x - v) * 0.5f;
                bool s = (v >= 1.f);
                p[i*256] = s ? 1.f : 0.f;
                v = s ? 0.f : v;
            }
        }
        __syncthreads();
        // ---- fc2: Y = LN(H_spk @ W2 + b2)  [TW,128] ----
        float2 gacc[4];
        #pragma unroll
        for (int rr = 0; rr < 4; ++rr) gacc[rr] = make_float2(0.f, 0.f);
        {
            const float* Hv = vptr(Hb);
            for (int h = 0; h < 2; ++h) {
                __syncthreads();
                const float4* Wh = (const float4*)(fc2w + (size_t)l*32768 + h*16384);
                for (int i = t; i < 4096; i += 1024) ((float4*)Wc)[i] = Wh[i];
                __syncthreads();
                #pragma unroll 2
                for (int k4 = 0; k4 < 32; ++k4) {
                    float4 xr[4];
                    #pragma unroll
                    for (int rr = 0; rr < 4; ++rr)
                        xr[rr] = *(const float4*)(Hv + (r0+rr)*256 + h*128 + k4*4);
                    #pragma unroll
                    for (int kk = 0; kk < 4; ++kk) {
                        float2 w = ((const float2*)(Wc + (k4*4 + kk)*128))[lane];
                        #pragma unroll
                        for (int rr = 0; rr < 4; ++rr) {
                            float xv = ((const float*)&xr[rr])[kk];
                            gacc[rr].x += xv * w.x;
                            gacc[rr].y += xv * w.y;
                        }
                    }
                }
            }
        }
        {
            float2 bv  = ((const float2*)(fc2b + l*128))[lane];
            float2 gv  = ((const float2*)(n2g  + l*128))[lane];
            float2 btv = ((const float2*)(n2b  + l*128))[lane];
            #pragma unroll
            for (int rr = 0; rr < 4; ++rr) {
                float2 a = gacc[rr];
                a.x += bv.x; a.y += bv.y;
                float s = a.x + a.y;
                #pragma unroll
                for (int m = 1; m < 64; m <<= 1) s += __shfl_xor(s, m, 64);
                float mean = s * (1.0f/128.0f);
                float dx = a.x - mean, dy = a.y - mean;
                float q = dx*dx + dy*dy;
                #pragma unroll
                for (int m = 1; m < 64; m <<= 1) q += __shfl_xor(q, m, 64);
                float inv = 1.0f / sqrtf(q * (1.0f/128.0f) + 1e-5f);
                float2 o;
                o.x = dx*inv*gv.x + btv.x;
                o.y = dy*inv*gv.y + btv.y;
                ((float2*)(Yb + (size_t)(r0+rr)*128))[lane] = o;
            }
        }
        __syncthreads();
        // ---- lif2 + residual into X; final-layer output (128 chains) ----
        if (t < 128) {
            const float* yp = Yb + t;
            float* xp = Xb + t;
            float v = 0.f, xlast = 0.f;
            #pragma unroll 8
            for (int i = 0; i < TW; ++i) {
                float y = yp[i*128];
                v += (y - v) * 0.5f;
                bool s = (v >= 1.f);
                float x = xp[i*128] + (s ? 1.f : 0.f);   // unconditional
                xp[i*128] = x;
                xlast = x;
                v = s ? 0.f : v;
            }
            if (l == 3) out[b*128 + t] = xlast;          // x[b, 2047, :]
        }
        __syncthreads();
    }
}

extern "C" void kernel_launch(void* const* d_in, const int* in_sizes, int n_in,
                              void* d_out, int out_size, void* d_ws, size_t ws_size,
                              hipStream_t stream) {
    const float* hist = (const float*)d_in[0];
    const float* pw1  = (const float*)d_in[1];
    const float* pb1  = (const float*)d_in[2];
    const float* pw2  = (const float*)d_in[3];
    const float* pb2  = (const float*)d_in[4];
    const float* fc1w = (const float*)d_in[5];
    const float* fc1b = (const float*)d_in[6];
    const float* n1g  = (const float*)d_in[7];
    const float* n1b  = (const float*)d_in[8];
    const float* fc2w = (const float*)d_in[9];
    const float* fc2b = (const float*)d_in[10];
    const float* n2g  = (const float*)d_in[11];
    const float* n2b  = (const float*)d_in[12];
    float* out = (float*)d_out;

    char* ws = (char*)d_ws;
    float* X = (float*)ws;                      // [NB][TW][128] f32: 2 MiB
    float* H = (float*)(ws + (4ull<<20));       // [NB][TW][256] f32: 4 MiB
    float* Y = (float*)(ws + (16ull<<20));      // [NB][TW][128] f32: 2 MiB
    float* G = (float*)(ws + (24ull<<20));      // [NB][TW][64]  f32: 1 MiB

    mega_kernel<<<NB, 1024, 0, stream>>>(hist, pw1, pb1, pw2, pb2,
                                         fc1w, fc1b, n1g, n1b,
                                         fc2w, fc2b, n2g, n2b,
                                         X, H, Y, G, out);
}

// Round 12
// 340.200 us; speedup vs baseline: 1.0424x; 1.0424x over previous
//
#include <hip/hip_runtime.h>
#include <math.h>

// Problem constants
#define NB   64
#define TT   2048
// Tail-window truncation (validated R6/R7): output = x[:,2047]; only temporal
// coupling is the LIF membrane (decay 0.5/step + hard reset). v(T0)=0 with
// TW=64 -> output perturbation ~0.5^63; absmax matched full scan exactly.
#define TW   64
#define T0   (TT - TW)

// Single plain launch, block = batch (R8 semantics — PROVEN correct: all
// cross-stage handoffs are same-CU, L1 write-through, __syncthreads only; no
// grid sync, no coop launch, no scalar-K$ exposure to same-kernel data).
// R8's 288us was a CONFIG failure, not structural: __launch_bounds__(1024,4)
// capped VGPRs at 64 (measured), serializing the row loads; 16 waves
// thrashed L1. This version: 512 thr (8 waves), no VGPR cap, 8 rows/wave,
// R7-proven inner loops (LDS weights via ds_read_b128 + wave-uniform vptr
// broadcast row loads), unroll-2 load batching.
// COOP NOTE (R9-R11): cooperative grid.sync variants failed 3x with a
// bit-identical single flipped spike across structural variants — mechanism
// never localized; cooperative fusion abandoned.

__device__ __forceinline__ float gelu_exact(float x) {
    return 0.5f * x * (1.0f + erff(x * 0.7071067811865476f));
}

// Route a pointer through a VGPR: forces vector-path loads (L1-coherent with
// this CU's own prior stores). Wave-uniform address -> HW-coalesced broadcast.
__device__ __forceinline__ const float* vptr(const float* p) {
    asm volatile("" : "+v"(p));
    return p;
}

__global__ __launch_bounds__(512, 1) void mega_kernel(
        const float* __restrict__ hist,
        const float* __restrict__ pw1, const float* __restrict__ pb1,
        const float* __restrict__ pw2, const float* __restrict__ pb2,
        const float* __restrict__ fc1w, const float* __restrict__ fc1b,
        const float* __restrict__ n1g, const float* __restrict__ n1b,
        const float* __restrict__ fc2w, const float* __restrict__ fc2b,
        const float* __restrict__ n2g, const float* __restrict__ n2b,
        char* ws, float* out)
{
    __shared__ float Wc[64*256];                 // 64 KB weight staging
    const int t    = threadIdx.x;                // 512 threads = 8 waves
    const int b    = blockIdx.x;                 // one block per batch
    const int wv   = t >> 6, lane = t & 63;
    const int r0   = wv * 8;                     // 8 rows per wave

    char* base = ws + (size_t)b * 262144;        // 256 KB per batch (16 MB tot)
    float* G = (float*)base;                     // [64][64]   16 KB
    float* X = (float*)(base + 16384);           // [64][128]  32 KB (in-place residual)
    float* H = (float*)(base + 65536);           // [64][256]  64 KB
    float* Y = (float*)(base + 131072);          // [64][128]  32 KB

    // ---------------- P1: G = gelu(hist @ pw1 + pb1)  [64,64] ---------------
    {
        const float* hb = hist + ((size_t)b * TT + T0) * 4;
        for (int e = t; e < 64*64; e += 512) {
            int r = e >> 6, j = e & 63;
            float a = pb1[j] + hb[r*4+0]*pw1[j]     + hb[r*4+1]*pw1[64+j]
                             + hb[r*4+2]*pw1[128+j] + hb[r*4+3]*pw1[192+j];
            G[e] = gelu_exact(a);
        }
        // stage pw2 (32 KB) concurrently
        for (int i = t; i < 64*128/4; i += 512)
            ((float4*)Wc)[i] = ((const float4*)pw2)[i];
    }
    __syncthreads();

    // ---------------- P2: X = G @ pw2 + pb2  [64,128] -----------------------
    {
        const float* x0 = vptr(G + r0*64);       // same-CU fresh, L1 broadcast
        float2 bv = ((const float2*)pb2)[lane];
        float2 acc[8];
        #pragma unroll
        for (int r = 0; r < 8; ++r) acc[r] = make_float2(0.f, 0.f);
        #pragma unroll 2
        for (int k4 = 0; k4 < 16; ++k4) {
            float4 xr[8];
            #pragma unroll
            for (int r = 0; r < 8; ++r)
                xr[r] = *(const float4*)(x0 + r*64 + k4*4);
            #pragma unroll
            for (int kk = 0; kk < 4; ++kk) {
                float2 w = ((const float2*)(Wc + (k4*4 + kk)*128))[lane];
                #pragma unroll
                for (int r = 0; r < 8; ++r) {
                    float xv = ((const float*)&xr[r])[kk];
                    acc[r].x += xv * w.x;
                    acc[r].y += xv * w.y;
                }
            }
        }
        #pragma unroll
        for (int r = 0; r < 8; ++r) {
            float2 o; o.x = acc[r].x + bv.x; o.y = acc[r].y + bv.y;
            ((float2*)(X + (size_t)(r0 + r)*128))[lane] = o;
        }
    }

    // ---------------- 4 residual blocks -------------------------------------
    for (int l = 0; l < 4; ++l) {
        // ---- fc1 + LN: H = LN(X @ W1 + b1)  [64,256] ----
        {
            const float* x0 = vptr(X + r0*128);
            float4 facc[8];
            #pragma unroll
            for (int r = 0; r < 8; ++r) facc[r] = make_float4(0.f,0.f,0.f,0.f);
            for (int h = 0; h < 2; ++h) {
                __syncthreads();                 // Wc free; also fences X writes
                const float4* Wh = (const float4*)(fc1w + (size_t)l*32768 + h*16384);
                for (int i = t; i < 4096; i += 512) ((float4*)Wc)[i] = Wh[i];
                __syncthreads();
                const float* xh = x0 + h*64;
                #pragma unroll 2
                for (int k4 = 0; k4 < 16; ++k4) {
                    float4 xr[8];
                    #pragma unroll
                    for (int r = 0; r < 8; ++r)
                        xr[r] = *(const float4*)(xh + r*128 + k4*4);
                    #pragma unroll
                    for (int kk = 0; kk < 4; ++kk) {
                        float4 w = ((const float4*)(Wc + (k4*4 + kk)*256))[lane];
                        #pragma unroll
                        for (int r = 0; r < 8; ++r) {
                            float xv = ((const float*)&xr[r])[kk];
                            facc[r].x += xv * w.x; facc[r].y += xv * w.y;
                            facc[r].z += xv * w.z; facc[r].w += xv * w.w;
                        }
                    }
                }
            }
            float4 bv  = ((const float4*)(fc1b + l*256))[lane];
            float4 gv  = ((const float4*)(n1g  + l*256))[lane];
            float4 btv = ((const float4*)(n1b  + l*256))[lane];
            #pragma unroll
            for (int r = 0; r < 8; ++r) {
                float4 a = facc[r];
                a.x += bv.x; a.y += bv.y; a.z += bv.z; a.w += bv.w;
                float s = a.x + a.y + a.z + a.w;
                #pragma unroll
                for (int m = 1; m < 64; m <<= 1) s += __shfl_xor(s, m, 64);
                float mean = s * (1.0f/256.0f);
                float dx = a.x-mean, dy = a.y-mean, dz = a.z-mean, dw = a.w-mean;
                float q = dx*dx + dy*dy + dz*dz + dw*dw;
                #pragma unroll
                for (int m = 1; m < 64; m <<= 1) q += __shfl_xor(q, m, 64);
                float inv = 1.0f / sqrtf(q * (1.0f/256.0f) + 1e-5f);
                float4 o;
                o.x = dx*inv*gv.x + btv.x; o.y = dy*inv*gv.y + btv.y;
                o.z = dz*inv*gv.z + btv.z; o.w = dw*inv*gv.w + btv.w;
                ((float4*)(H + (size_t)(r0 + r)*256))[lane] = o;
            }
        }
        __syncthreads();

        // ---- lif1: H -> spike floats in place (256 chains, same CU) ----
        if (t < 256) {
            float* p = H + t;
            float v = 0.f;
            #pragma unroll 8
            for (int i = 0; i < TW; ++i) {
                float x = p[i*256];
                v += (x - v) * 0.5f;
                bool s = (v >= 1.f);
                p[i*256] = s ? 1.f : 0.f;
                v = s ? 0.f : v;
            }
        }
        __syncthreads();

        // ---- fc2 + LN: Y = LN(H_spk @ W2 + b2)  [64,128] ----
        {
            const float* s0 = vptr(H + r0*256);
            float2 gacc[8];
            #pragma unroll
            for (int r = 0; r < 8; ++r) gacc[r] = make_float2(0.f, 0.f);
            for (int h = 0; h < 2; ++h) {
                __syncthreads();
                const float4* Wh = (const float4*)(fc2w + (size_t)l*32768 + h*16384);
                for (int i = t; i < 4096; i += 512) ((float4*)Wc)[i] = Wh[i];
                __syncthreads();
                const float* xh = s0 + h*128;
                #pragma unroll 2
                for (int k4 = 0; k4 < 32; ++k4) {
                    float4 xr[8];
                    #pragma unroll
                    for (int r = 0; r < 8; ++r)
                        xr[r] = *(const float4*)(xh + r*256 + k4*4);
                    #pragma unroll
                    for (int kk = 0; kk < 4; ++kk) {
                        float2 w = ((const float2*)(Wc + (k4*4 + kk)*128))[lane];
                        #pragma unroll
                        for (int r = 0; r < 8; ++r) {
                            float xv = ((const float*)&xr[r])[kk];
                            gacc[r].x += xv * w.x;
                            gacc[r].y += xv * w.y;
                        }
                    }
                }
            }
            float2 bv  = ((const float2*)(fc2b + l*128))[lane];
            float2 gv  = ((const float2*)(n2g  + l*128))[lane];
            float2 btv = ((const float2*)(n2b  + l*128))[lane];
            #pragma unroll
            for (int r = 0; r < 8; ++r) {
                float2 a = gacc[r];
                a.x += bv.x; a.y += bv.y;
                float s = a.x + a.y;
                #pragma unroll
                for (int m = 1; m < 64; m <<= 1) s += __shfl_xor(s, m, 64);
                float mean = s * (1.0f/128.0f);
                float dx = a.x - mean, dy = a.y - mean;
                float q = dx*dx + dy*dy;
                #pragma unroll
                for (int m = 1; m < 64; m <<= 1) q += __shfl_xor(q, m, 64);
                float inv = 1.0f / sqrtf(q * (1.0f/128.0f) + 1e-5f);
                float2 o;
                o.x = dx*inv*gv.x + btv.x;
                o.y = dy*inv*gv.y + btv.y;
                ((float2*)(Y + (size_t)(r0 + r)*128))[lane] = o;
            }
        }
        __syncthreads();

        // ---- lif2 + residual in place on X; final-layer output ----
        if (t < 128) {
            const float* yp = Y + t;
            float* xp = X + t;
            float v = 0.f, xlast = 0.f;
            #pragma unroll 8
            for (int i = 0; i < TW; ++i) {
                float y = yp[i*128];
                v += (y - v) * 0.5f;
                bool s = (v >= 1.f);
                float x = xp[i*128] + (s ? 1.f : 0.f);   // unconditional
                xp[i*128] = x;
                xlast = x;
                v = s ? 0.f : v;
            }
            if (l == 3) out[b*128 + t] = xlast;          // x[b, 2047, :]
        }
        __syncthreads();
    }
}

extern "C" void kernel_launch(void* const* d_in, const int* in_sizes, int n_in,
                              void* d_out, int out_size, void* d_ws, size_t ws_size,
                              hipStream_t stream) {
    const float* hist = (const float*)d_in[0];
    const float* pw1  = (const float*)d_in[1];
    const float* pb1  = (const float*)d_in[2];
    const float* pw2  = (const float*)d_in[3];
    const float* pb2  = (const float*)d_in[4];
    const float* fc1w = (const float*)d_in[5];
    const float* fc1b = (const float*)d_in[6];
    const float* n1g  = (const float*)d_in[7];
    const float* n1b  = (const float*)d_in[8];
    const float* fc2w = (const float*)d_in[9];
    const float* fc2b = (const float*)d_in[10];
    const float* n2g  = (const float*)d_in[11];
    const float* n2b  = (const float*)d_in[12];
    float* out = (float*)d_out;
    char* ws = (char*)d_ws;

    mega_kernel<<<NB, 512, 0, stream>>>(hist, pw1, pb1, pw2, pb2,
                                        fc1w, fc1b, n1g, n1b,
                                        fc2w, fc2b, n2g, n2b,
                                        ws, out);
}